// Round 2
// baseline (251.545 us; speedup 1.0000x reference)
//
#include <hip/hip_runtime.h>
#include <math.h>

#define NEG_BIG  (-1e30f)
#define NEG_H16  (-60000.0f)   // "empty" marker safe in fp16

typedef _Float16 half8  __attribute__((ext_vector_type(8)));
typedef _Float16 half2v __attribute__((ext_vector_type(2)));
typedef float    floatx4 __attribute__((ext_vector_type(4)));

// ---------------------------------------------------------------------------
// Kernel 0 (fused aux), 177 blocks:
//   blocks 0..47  : feat fp32->fp16, 8 elems/thread (vectorized)
//   block  48     : per-LR-pixel folded constants PA/PB/PS
//   blocks 49..176: 128 LC tables [Pu][Pv][(R-1)*2+vcb] fp16 = ln(mult)
// ---------------------------------------------------------------------------
__global__ __launch_bounds__(256) void setup_all(
    const float* __restrict__ feat, const float* __restrict__ guide,
    const float* __restrict__ sx_raw, const float* __restrict__ sy_raw,
    const float* __restrict__ th_raw, const float* __restrict__ sr_raw,
    _Float16* __restrict__ feat16, float4* __restrict__ PA,
    float4* __restrict__ PB, float* __restrict__ PS,
    _Float16* __restrict__ LCtab)
{
    const int b = blockIdx.x, t = threadIdx.x;
    if (b < 48) {
        int i = (b*256 + t)*8;
        float4 f0 = *(const float4*)(feat + i);
        float4 f1 = *(const float4*)(feat + i + 4);
        half8 h;
        h[0]=(_Float16)f0.x; h[1]=(_Float16)f0.y; h[2]=(_Float16)f0.z; h[3]=(_Float16)f0.w;
        h[4]=(_Float16)f1.x; h[5]=(_Float16)f1.y; h[6]=(_Float16)f1.z; h[7]=(_Float16)f1.w;
        *(half8*)(feat16 + i) = h;
        return;
    }
    if (b == 48) {
        float sx = expf(sx_raw[t]);
        float sy = expf(sy_raw[t]);
        float th = 3.14159265358979323846f * tanhf(th_raw[t]);
        float sr = expf(sr_raw[t]);
        float sxg = fmaxf(sx, 1e-6f), syg = fmaxf(sy, 1e-6f), srg = fmaxf(sr, 1e-6f);
        float iA = 1.f / (2.f*sxg*sxg + 1e-8f);
        float iB = 1.f / (2.f*syg*syg + 1e-8f);
        float iC = 1.f / (2.f*srg*srg + 1e-8f);
        float ct = cosf(th), st = sinf(th);
        float A2 = iA*ct*ct + iB*st*st;
        float B2 = 2.f*ct*st*(iA - iB);
        float C2 = iA*st*st + iB*ct*ct;
        PA[t] = make_float4(-A2, -B2, -C2, -iC);
        int i = t >> 4, j = t & 15;
        int y0 = 16*i + 7, x0 = 16*j + 7;   // bilinear 256->16 == 2x2 average
        float g[3];
#pragma unroll
        for (int c = 0; c < 3; ++c) {
            const float* gp = guide + c*65536;
            g[c] = 0.25f*(gp[y0*256 + x0]     + gp[y0*256 + x0 + 1] +
                          gp[(y0+1)*256 + x0] + gp[(y0+1)*256 + x0 + 1]);
        }
        PB[t] = make_float4(2.f*iC*g[0], 2.f*iC*g[1], 2.f*iC*g[2],
                            -iC*(g[0]*g[0] + g[1]*g[1] + g[2]*g[2]));
        PS[t] = fmaxf(sx, sy);
        return;
    }
    // ---- LC tables (identical math to verified round-1 build) ----
    const int tb  = b - 49;           // 0..127
    const int uc  = tb >> 3;          // 0..15
    const int vc0 = (tb & 7) << 1;    // == X0>>4
    const int Pu  = t >> 4;
    const int col = t & 15;
    const int Rt  = (col >> 1) + 1;
    const int vc  = vc0 + (col & 1);
    const int R2  = Rt * Rt;
    int ylo = (Pu == 0)  ? -8 : (Pu - uc);
    int yhi = (Pu == 15) ?  8 : (Pu - uc);
    ylo = max(ylo, -8); yhi = min(yhi, 8);
    int cnt[16];
#pragma unroll
    for (int Pv = 1; Pv < 15; ++Pv) {
        int d = Pv - vc;
        int lim = R2 - d*d;
        int c = 0;
        if (lim >= 0 && ylo <= yhi) {
            int s = (int)sqrtf((float)lim);   // exact for ints <= 64
            c = max(0, min(yhi, s) - max(ylo, -s) + 1);
        }
        cnt[Pv] = c;
    }
    cnt[0] = 0;
    if (-vc >= -8) {
        for (int dY = ylo; dY <= yhi; ++dY) {
            int lim = R2 - dY*dY;
            if (lim >= 0) {
                int r = (int)sqrtf((float)lim);
                cnt[0] += max(0, min(-vc, r) + r + 1);
            }
        }
    }
    cnt[15] = 0;
    if (15 - vc <= 8) {
        for (int dY = ylo; dY <= yhi; ++dY) {
            int lim = R2 - dY*dY;
            if (lim >= 0) {
                int r = (int)sqrtf((float)lim);
                cnt[15] += max(0, r - max(15 - vc, -r) + 1);
            }
        }
    }
    _Float16* dst = LCtab + (size_t)tb * 4096;
#pragma unroll
    for (int Pv = 0; Pv < 16; ++Pv)
        dst[(Pu*16 + Pv)*16 + col] = (_Float16)
            ((cnt[Pv] > 0) ? __logf((float)cnt[Pv]) : NEG_H16);
}

// ---------------------------------------------------------------------------
// Kernel 1: main fused JBU. Occupancy-targeted rebuild of the verified round-1
// structure:
//   - LDS 25 KB (Wb 16K + Sg 8K + red 1K) -> 6 blocks/CU
//   - two-pass max (no lw[32]) + two-mt-pass MFMA (acc 24) -> ~84 unified regs
//   - PA/PB staged in Sg (dead until post-B3); LC read from global (L2-hot)
//   - XCD-band grid swizzle for HBM write page locality
// ---------------------------------------------------------------------------
__global__ __launch_bounds__(256, 6) void jbu_main(
    const float* __restrict__ guide, const _Float16* __restrict__ feat16,
    const float4* __restrict__ PA, const float4* __restrict__ PB,
    const float* __restrict__ PS, const _Float16* __restrict__ LCtab,
    float* __restrict__ out)
{
    __shared__ __align__(16) _Float16 Wb[32][256];  // 16 KB, row=pixel, swizzled
    __shared__ __align__(16) float Sg[2048];        // 8 KB: PA/PB early, epilogue late
    __shared__ float redM[4][32];                   // per-wave max partials
    __shared__ float redD[4][32];                   // per-wave den partials

    const int t   = threadIdx.x;
    const int q   = t & 31;
    const int grp = t >> 5;
    const int wv  = t >> 6;

    // ---- XCD-band swizzle: XCD k owns rows Y==k (mod 8); consecutive slots
    //      on one XCD are the 8 X-strips of one row (contiguous 1KB writes) ----
    const int n   = blockIdx.x;
    const int xcd = n & 7;
    const int s   = n >> 3;
    const int bx  = s & 7;
    const int Y   = ((s >> 3) << 3) + xcd;
    const int X0  = bx << 5;
    const int X   = X0 + q;
    const float Yf = (float)Y, Xf = (float)X;
    const int uc   = Y >> 4;          // == clip(round(u),0,15) exactly

    // ---- Stage PA/PB into Sg (aliased; last read pre-B3) ----
    ((float4*)Sg)[t]       = PA[t];
    ((float4*)Sg)[256 + t] = PB[t];

    // ---- Per-pixel R from bilinear upsample of max(sx,sy) ----
    float u = (Yf + 0.5f)*0.0625f - 0.5f;
    float v = (Xf + 0.5f)*0.0625f - 0.5f;
    float ysc = fmaxf(u, 0.f), xsc = fmaxf(v, 0.f);
    int y0 = (int)ysc, x0 = (int)xsc;
    int y1 = min(y0 + 1, 15), x1 = min(x0 + 1, 15);
    float wy = ysc - (float)y0, wx = xsc - (float)x0;
    float s00 = PS[y0*16 + x0], s01 = PS[y0*16 + x1];
    float s10 = PS[y1*16 + x0], s11 = PS[y1*16 + x1];
    float sig = (1.f - wy)*((1.f - wx)*s00 + wx*s01)
              +        wy *((1.f - wx)*s10 + wx*s11);
    float Rf = fminf(fmaxf(ceilf(2.f*sig), 1.f), 8.f);
    const int colq = ((int)Rf - 1)*2 + (q >> 4);   // vcb = q>>4

    const float g0 = guide[          (Y << 8) + X];
    const float g1 = guide[ 65536 + ((Y << 8) + X)];
    const float g2 = guide[131072 + ((Y << 8) + X)];
    const float g2s = g0*g0 + g1*g1 + g2*g2;

    // per-thread LC base (global, L1/L2-hot 8 KB slice)
    const _Float16* Lbase = LCtab + (size_t)(uc*8 + bx)*4096 + colq;

    const int pbase = grp << 5;
    const float dy0  = Yf - (32.f*(float)grp + 7.5f);
    const float dy1  = dy0 - 16.f;
    const float dy20 = dy0*dy0, dy21 = dy1*dy1;

    __syncthreads();   // B1: publishes Sg (PA/PB)

    // ---- Phase A: running max only (no lw[] storage) ----
    float mloc = NEG_BIG;
#pragma unroll
    for (int col = 0; col < 16; ++col) {
        float dx    = Xf - (16.f*(float)col + 7.5f);
        float dx2   = dx*dx;
        float dxdy0 = dx*dy0, dxdy1 = dx*dy1;
#pragma unroll
        for (int row = 0; row < 2; ++row) {
            int p = pbase + row*16 + col;
            float4 A = ((const float4*)Sg)[p];
            float4 B = ((const float4*)Sg)[256 + p];
            float w = fmaf(B.x, g0, B.w);
            w = fmaf(B.y, g1, w);
            w = fmaf(B.z, g2, w);
            w = fmaf(A.w, g2s, w);
            w = fmaf(A.x, dx2, w);
            w = fmaf(A.y, row ? dxdy1 : dxdy0, w);
            w = fmaf(A.z, row ? dy21  : dy20,  w);
            w += (float)Lbase[p*16];
            mloc = fmaxf(mloc, w);
        }
    }
    mloc = fmaxf(mloc, __shfl_xor(mloc, 32, 64));  // combine wave's 2 p-groups
    redM[wv][q] = mloc;
    __syncthreads();   // B2
    const float m = fmaxf(fmaxf(redM[0][q], redM[1][q]),
                          fmaxf(redM[2][q], redM[3][q]));

    // ---- Phase B: recompute w (bit-identical chain), exp, fp16, Wb, den ----
    float dloc = 0.f;
#pragma unroll
    for (int row = 0; row < 2; ++row) {
        const float dy  = row ? dy1  : dy0;
        const float dy2 = row ? dy21 : dy20;
#pragma unroll
        for (int col = 0; col < 16; col += 2) {
            float e[2];
#pragma unroll
            for (int k = 0; k < 2; ++k) {
                int cc = col + k;
                int p  = pbase + row*16 + cc;
                float dx = Xf - (16.f*(float)cc + 7.5f);
                float4 A = ((const float4*)Sg)[p];
                float4 B = ((const float4*)Sg)[256 + p];
                float w = fmaf(B.x, g0, B.w);
                w = fmaf(B.y, g1, w);
                w = fmaf(B.z, g2, w);
                w = fmaf(A.w, g2s, w);
                w = fmaf(A.x, dx*dx, w);
                w = fmaf(A.y, dx*dy, w);
                w = fmaf(A.z, dy2, w);
                w += (float)Lbase[p*16];
                e[k] = __expf(w - m);     // empty entries underflow to 0
            }
            half2v hh; hh[0] = (_Float16)e[0]; hh[1] = (_Float16)e[1];
            int p0 = pbase + row*16 + col;
            int chunk = ((p0 >> 3) ^ q) & 31;     // 16B-chunk XOR swizzle
            *(half2v*)&Wb[q][chunk*8 + (p0 & 7)] = hh;
            dloc += (float)hh[0] + (float)hh[1];  // den consistent w/ fp16 weights
        }
    }
    dloc += __shfl_xor(dloc, 32, 64);
    redD[wv][q] = dloc;
    __syncthreads();   // B3: publishes Wb + redD; Sg (PA/PB) now dead

    // ---- Phase 3: two mt-passes of MFMA (acc 24), each with staged epilogue ----
    const int lane = t & 63;
    const int mrow = lane & 15;
    const int quad = lane >> 4;
    const int c0   = wv * 96;

    float idv[2];
#pragma unroll
    for (int nt = 0; nt < 2; ++nt) {
        int pix = nt*16 + mrow;
        float den = redD[0][pix] + redD[1][pix] + redD[2][pix] + redD[3][pix];
        idv[nt] = 1.f / fmaxf(den, 1e-8f);
    }

    float* Sf = Sg + (wv << 9);              // 512 floats per wave
    const int sch = lane >> 3;               // 0..7   channel sub-row
    const int spg = lane & 7;                // 0..7   pixel 4-group
    const int outcol = (Y << 8) + X0;

#pragma unroll
    for (int pass = 0; pass < 2; ++pass) {
        floatx4 acc[3][2] = {};
        const _Float16* fbase = feat16 + (c0 + pass*48 + mrow)*256 + quad*8;
#pragma unroll
        for (int ks = 0; ks < 8; ++ks) {
            half8 a[3];
#pragma unroll
            for (int mt = 0; mt < 3; ++mt)
                a[mt] = *(const half8*)(fbase + mt*16*256 + ks*32);
            half8 b[2];
#pragma unroll
            for (int nt = 0; nt < 2; ++nt) {
                int pix = nt*16 + mrow;
                int chunk = ((ks*4 + quad) ^ pix) & 31;
                b[nt] = *(const half8*)(&Wb[pix][chunk*8]);
            }
#pragma unroll
            for (int mt = 0; mt < 3; ++mt)
#pragma unroll
                for (int nt = 0; nt < 2; ++nt)
                    acc[mt][nt] = __builtin_amdgcn_mfma_f32_16x16x32_f16(
                        a[mt], b[nt], acc[mt][nt], 0, 0, 0);
        }
        // Epilogue for this pass: stage (8*quad-rotated) -> dwordx4 stores.
#pragma unroll
        for (int mt = 0; mt < 3; ++mt) {
#pragma unroll
            for (int nt = 0; nt < 2; ++nt) {
                const int cxx = nt*16 + mrow;
#pragma unroll
                for (int r = 0; r < 4; ++r) {
                    int row = quad*4 + r;
                    Sf[row*32 + ((cxx + 8*quad) & 31)] = acc[mt][nt][r] * idv[nt];
                }
            }
            // wave-synchronous RAW on same LDS alloc: compiler inserts lgkmcnt
#pragma unroll
            for (int j = 0; j < 2; ++j) {
                int row = j*8 + sch;
                float4 vv = *(const float4*)&Sf[row*32 + ((spg*4 + 8*(row >> 2)) & 31)];
                *(float4*)(out + (size_t)(c0 + pass*48 + mt*16 + row)*65536
                               + outcol + spg*4) = vv;
            }
        }
    }
}

// ---------------------------------------------------------------------------
extern "C" void kernel_launch(void* const* d_in, const int* in_sizes, int n_in,
                              void* d_out, int out_size, void* d_ws, size_t ws_size,
                              hipStream_t stream)
{
    const float* feat   = (const float*)d_in[0];   // [1,384,16,16]
    const float* guide  = (const float*)d_in[1];   // [1,3,256,256]
    const float* sx_raw = (const float*)d_in[2];   // [1,1,16,16]
    const float* sy_raw = (const float*)d_in[3];
    const float* th_raw = (const float*)d_in[4];
    const float* sr_raw = (const float*)d_in[5];
    float* out = (float*)d_out;                    // [1,384,256,256]

    char* ws = (char*)d_ws;
    _Float16* feat16 = (_Float16*)ws;                    // 192 KB @ 0
    float4*   PA     = (float4*)(ws + 196608);           // 4 KB
    float4*   PB     = (float4*)(ws + 200704);           // 4 KB
    float*    PS     = (float*)(ws + 204800);            // 1 KB
    _Float16* LCtab  = (_Float16*)(ws + 205824);         // 1 MB (128 x 8 KB)

    setup_all<<<177, 256, 0, stream>>>(feat, guide, sx_raw, sy_raw, th_raw,
                                       sr_raw, feat16, PA, PB, PS, LCtab);
    jbu_main<<<2048, 256, 0, stream>>>(guide, feat16, PA, PB, PS, LCtab, out);
}

// Round 3
// 161.837 us; speedup vs baseline: 1.5543x; 1.5543x over previous
//
#include <hip/hip_runtime.h>
#include <math.h>

#define NEG_BIG  (-1e30f)
#define NEG_H16  (-60000.0f)   // "empty" marker safe in fp16

typedef _Float16 half8  __attribute__((ext_vector_type(8)));
typedef _Float16 half2v __attribute__((ext_vector_type(2)));
typedef float    floatx4 __attribute__((ext_vector_type(4)));

// ---------------------------------------------------------------------------
// Kernel 0 (fused aux), 177 blocks:
//   blocks 0..47  : feat fp32->fp16, 8 elems/thread (vectorized)
//   block  48     : per-LR-pixel folded constants PA/PB/PS
//   blocks 49..176: 128 LC tables [Pu][Pv][(R-1)*2+vcb] fp16 = ln(mult)
// ---------------------------------------------------------------------------
__global__ __launch_bounds__(256) void setup_all(
    const float* __restrict__ feat, const float* __restrict__ guide,
    const float* __restrict__ sx_raw, const float* __restrict__ sy_raw,
    const float* __restrict__ th_raw, const float* __restrict__ sr_raw,
    _Float16* __restrict__ feat16, float4* __restrict__ PA,
    float4* __restrict__ PB, float* __restrict__ PS,
    _Float16* __restrict__ LCtab)
{
    const int b = blockIdx.x, t = threadIdx.x;
    if (b < 48) {
        int i = (b*256 + t)*8;
        float4 f0 = *(const float4*)(feat + i);
        float4 f1 = *(const float4*)(feat + i + 4);
        half8 h;
        h[0]=(_Float16)f0.x; h[1]=(_Float16)f0.y; h[2]=(_Float16)f0.z; h[3]=(_Float16)f0.w;
        h[4]=(_Float16)f1.x; h[5]=(_Float16)f1.y; h[6]=(_Float16)f1.z; h[7]=(_Float16)f1.w;
        *(half8*)(feat16 + i) = h;
        return;
    }
    if (b == 48) {
        float sx = expf(sx_raw[t]);
        float sy = expf(sy_raw[t]);
        float th = 3.14159265358979323846f * tanhf(th_raw[t]);
        float sr = expf(sr_raw[t]);
        float sxg = fmaxf(sx, 1e-6f), syg = fmaxf(sy, 1e-6f), srg = fmaxf(sr, 1e-6f);
        float iA = 1.f / (2.f*sxg*sxg + 1e-8f);
        float iB = 1.f / (2.f*syg*syg + 1e-8f);
        float iC = 1.f / (2.f*srg*srg + 1e-8f);
        float ct = cosf(th), st = sinf(th);
        float A2 = iA*ct*ct + iB*st*st;
        float B2 = 2.f*ct*st*(iA - iB);
        float C2 = iA*st*st + iB*ct*ct;
        PA[t] = make_float4(-A2, -B2, -C2, -iC);
        int i = t >> 4, j = t & 15;
        int y0 = 16*i + 7, x0 = 16*j + 7;   // bilinear 256->16 == 2x2 average
        float g[3];
#pragma unroll
        for (int c = 0; c < 3; ++c) {
            const float* gp = guide + c*65536;
            g[c] = 0.25f*(gp[y0*256 + x0]     + gp[y0*256 + x0 + 1] +
                          gp[(y0+1)*256 + x0] + gp[(y0+1)*256 + x0 + 1]);
        }
        PB[t] = make_float4(2.f*iC*g[0], 2.f*iC*g[1], 2.f*iC*g[2],
                            -iC*(g[0]*g[0] + g[1]*g[1] + g[2]*g[2]));
        PS[t] = fmaxf(sx, sy);
        return;
    }
    // ---- LC tables (identical math to the verified round-1 build) ----
    const int tb  = b - 49;           // 0..127
    const int uc  = tb >> 3;          // 0..15
    const int vc0 = (tb & 7) << 1;    // == X0>>4
    const int Pu  = t >> 4;
    const int col = t & 15;
    const int Rt  = (col >> 1) + 1;
    const int vc  = vc0 + (col & 1);
    const int R2  = Rt * Rt;
    int ylo = (Pu == 0)  ? -8 : (Pu - uc);
    int yhi = (Pu == 15) ?  8 : (Pu - uc);
    ylo = max(ylo, -8); yhi = min(yhi, 8);
    int cnt[16];
#pragma unroll
    for (int Pv = 1; Pv < 15; ++Pv) {
        int d = Pv - vc;
        int lim = R2 - d*d;
        int c = 0;
        if (lim >= 0 && ylo <= yhi) {
            int s = (int)sqrtf((float)lim);   // exact for ints <= 64
            c = max(0, min(yhi, s) - max(ylo, -s) + 1);
        }
        cnt[Pv] = c;
    }
    cnt[0] = 0;
    if (-vc >= -8) {
        for (int dY = ylo; dY <= yhi; ++dY) {
            int lim = R2 - dY*dY;
            if (lim >= 0) {
                int r = (int)sqrtf((float)lim);
                cnt[0] += max(0, min(-vc, r) + r + 1);
            }
        }
    }
    cnt[15] = 0;
    if (15 - vc <= 8) {
        for (int dY = ylo; dY <= yhi; ++dY) {
            int lim = R2 - dY*dY;
            if (lim >= 0) {
                int r = (int)sqrtf((float)lim);
                cnt[15] += max(0, r - max(15 - vc, -r) + 1);
            }
        }
    }
    _Float16* dst = LCtab + (size_t)tb * 4096;
#pragma unroll
    for (int Pv = 0; Pv < 16; ++Pv)
        dst[(Pu*16 + Pv)*16 + col] = (_Float16)
            ((cnt[Pv] > 0) ? __logf((float)cnt[Pv]) : NEG_H16);
}

// ---------------------------------------------------------------------------
// Kernel 1: main fused JBU — 512-thread (8-wave) restructure of the verified
// round-1 kernel. Per-element math is identical; only the thread->work map
// changes:
//   - phase 1/2: each thread owns 16 p's (one LR row), lw[16] in regs
//   - phase 3 : each wave owns 48 channels (acc[3][2] = 24 accs)
//   - epilogue: per-wave staging reuses Wb AFTER barrier B4
// Structural reg relief (acc 48->24, a 24->12, lw 32->16) buys occupancy
// without launch-bounds coercion (R2's spill lesson).
// LDS = 16 (Wb) + 8 (PA/PB) + 8 (LCh) + 2 (red) = 34 KB.
// ---------------------------------------------------------------------------
__global__ __launch_bounds__(512) void jbu_main(
    const float* __restrict__ guide, const _Float16* __restrict__ feat16,
    const float4* __restrict__ PA, const float4* __restrict__ PB,
    const float* __restrict__ PS, const _Float16* __restrict__ LCtab,
    float* __restrict__ out)
{
    __shared__ __align__(16) _Float16 Wb[32][256];  // 16 KB; epilogue staging post-B4
    __shared__ float4 sPA[256];                     // 4 KB
    __shared__ float4 sPB[256];                     // 4 KB
    __shared__ __align__(16) _Float16 LCh[4096];    // 8 KB
    __shared__ float redM[8][32];                   // per-wave max partials
    __shared__ float redD[8][32];                   // per-wave den partials

    const int t   = threadIdx.x;
    const int q   = t & 31;
    const int grp = t >> 5;    // 0..15: LR row Pu owned by this thread
    const int wv  = t >> 6;    // 0..7
    const int Y   = blockIdx.y;
    const int X0  = blockIdx.x << 5;
    const int X   = X0 + q;
    const float Yf = (float)Y, Xf = (float)X;
    const int uc   = Y >> 4;          // == clip(round(u),0,15) exactly

    // ---- Stage PA/PB (split across thread halves) + LC slice (L2-hot) ----
    if (t < 256) sPA[t] = PA[t];
    else         sPB[t & 255] = PB[t & 255];
    {
        const float4* Lsrc =
            (const float4*)(LCtab + (size_t)(uc*8 + blockIdx.x) * 4096);
        ((float4*)LCh)[t] = Lsrc[t];   // 512 threads x 16B = 8 KB
    }

    // ---- Per-pixel R from bilinear upsample of max(sx,sy) ----
    float u = (Yf + 0.5f)*0.0625f - 0.5f;
    float v = (Xf + 0.5f)*0.0625f - 0.5f;
    float ysc = fmaxf(u, 0.f), xsc = fmaxf(v, 0.f);
    int y0 = (int)ysc, x0 = (int)xsc;
    int y1 = min(y0 + 1, 15), x1 = min(x0 + 1, 15);
    float wy = ysc - (float)y0, wx = xsc - (float)x0;
    float s00 = PS[y0*16 + x0], s01 = PS[y0*16 + x1];
    float s10 = PS[y1*16 + x0], s11 = PS[y1*16 + x1];
    float sig = (1.f - wy)*((1.f - wx)*s00 + wx*s01)
              +        wy *((1.f - wx)*s10 + wx*s11);
    float Rf = fminf(fmaxf(ceilf(2.f*sig), 1.f), 8.f);
    const int colq = ((int)Rf - 1)*2 + (q >> 4);   // vcb = q>>4

    const float g0 = guide[          (Y << 8) + X];
    const float g1 = guide[ 65536 + ((Y << 8) + X)];
    const float g2 = guide[131072 + ((Y << 8) + X)];
    const float g2s = g0*g0 + g1*g1 + g2*g2;

    __syncthreads();   // B1: publishes sPA, sPB, LCh

    // ---- Phase 1: lw = ln(cnt) + folded 7-FMA chain (one LR row/thread) ----
    const int pbase = grp << 4;
    const float dy  = Yf - (16.f*(float)grp + 7.5f);
    const float dy2 = dy*dy;
    float lw[16];
    float mloc = NEG_BIG;
#pragma unroll
    for (int col = 0; col < 16; ++col) {
        int p = pbase + col;
        float dx = Xf - (16.f*(float)col + 7.5f);
        float4 A = sPA[p];
        float4 B = sPB[p];
        float w = fmaf(B.x, g0, B.w);
        w = fmaf(B.y, g1, w);
        w = fmaf(B.z, g2, w);
        w = fmaf(A.w, g2s, w);
        w = fmaf(A.x, dx*dx, w);
        w = fmaf(A.y, dx*dy, w);
        w = fmaf(A.z, dy2, w);
        w += (float)LCh[p*16 + colq];
        lw[col] = w;
        mloc = fmaxf(mloc, w);
    }
    mloc = fmaxf(mloc, __shfl_xor(mloc, 32, 64));  // combine wave's 2 rows
    redM[wv][q] = mloc;
    __syncthreads();   // B2
    const float m = fmaxf(fmaxf(fmaxf(redM[0][q], redM[1][q]),
                                fmaxf(redM[2][q], redM[3][q])),
                          fmaxf(fmaxf(redM[4][q], redM[5][q]),
                                fmaxf(redM[6][q], redM[7][q])));

    // ---- Phase 2: exp, fp16 round, paired swizzled LDS stores, den ----
    float dloc = 0.f;
#pragma unroll
    for (int col = 0; col < 16; col += 2) {
        int p0 = pbase + col;
        float e0 = __expf(lw[col]     - m);   // empty entries underflow to 0
        float e1 = __expf(lw[col + 1] - m);
        half2v hh; hh[0] = (_Float16)e0; hh[1] = (_Float16)e1;
        int chunk = ((p0 >> 3) ^ q) & 31;     // 16B-chunk XOR swizzle
        *(half2v*)&Wb[q][chunk*8 + (p0 & 7)] = hh;
        dloc += (float)hh[0] + (float)hh[1];  // den consistent with fp16 weights
    }
    dloc += __shfl_xor(dloc, 32, 64);
    redD[wv][q] = dloc;
    __syncthreads();   // B3: publishes Wb + redD

    // ---- Phase 3: MFMA GEMM, 48 channels per wave ----
    const int lane = t & 63;
    const int mrow = lane & 15;
    const int quad = lane >> 4;
    const int c0   = wv * 48;

    float idv[2];
#pragma unroll
    for (int nt = 0; nt < 2; ++nt) {
        int pix = nt*16 + mrow;
        float den = ((redD[0][pix] + redD[1][pix]) + (redD[2][pix] + redD[3][pix]))
                  + ((redD[4][pix] + redD[5][pix]) + (redD[6][pix] + redD[7][pix]));
        idv[nt] = 1.f / fmaxf(den, 1e-8f);
    }

    floatx4 acc[3][2] = {};
    const _Float16* fbase = feat16 + (c0 + mrow)*256 + quad*8;

#pragma unroll
    for (int ks = 0; ks < 8; ++ks) {
        half8 a[3];
#pragma unroll
        for (int mt = 0; mt < 3; ++mt)
            a[mt] = *(const half8*)(fbase + mt*16*256 + ks*32);
        half8 b[2];
#pragma unroll
        for (int nt = 0; nt < 2; ++nt) {
            int pix = nt*16 + mrow;
            int chunk = ((ks*4 + quad) ^ pix) & 31;
            b[nt] = *(const half8*)(&Wb[pix][chunk*8]);
        }
#pragma unroll
        for (int mt = 0; mt < 3; ++mt)
#pragma unroll
            for (int nt = 0; nt < 2; ++nt)
                acc[mt][nt] = __builtin_amdgcn_mfma_f32_16x16x32_f16(
                    a[mt], b[nt], acc[mt][nt], 0, 0, 0);
    }

    __syncthreads();   // B4: all Wb reads done; Wb becomes epilogue staging

    // ---- Epilogue: per-wave LDS transpose (2 KB slice of Wb) -> dwordx4 ----
    float* Sf = (float*)Wb + (wv << 9);      // 512 floats per wave
    const int sch = lane >> 3;               // 0..7   channel sub-row
    const int spg = lane & 7;                // 0..7   pixel 4-group
    const int outcol = (Y << 8) + X0;
#pragma unroll
    for (int mt = 0; mt < 3; ++mt) {
#pragma unroll
        for (int nt = 0; nt < 2; ++nt)
#pragma unroll
            for (int r = 0; r < 4; ++r)
                Sf[(quad*4 + r)*32 + nt*16 + mrow] = acc[mt][nt][r] * idv[nt];
        // wave-synchronous RAW on same LDS alloc: compiler inserts lgkmcnt wait
#pragma unroll
        for (int j = 0; j < 2; ++j) {
            float4 vv = *(const float4*)&Sf[(j*8 + sch)*32 + spg*4];
            *(float4*)(out + (size_t)(c0 + mt*16 + j*8 + sch)*65536
                           + outcol + spg*4) = vv;
        }
    }
}

// ---------------------------------------------------------------------------
extern "C" void kernel_launch(void* const* d_in, const int* in_sizes, int n_in,
                              void* d_out, int out_size, void* d_ws, size_t ws_size,
                              hipStream_t stream)
{
    const float* feat   = (const float*)d_in[0];   // [1,384,16,16]
    const float* guide  = (const float*)d_in[1];   // [1,3,256,256]
    const float* sx_raw = (const float*)d_in[2];   // [1,1,16,16]
    const float* sy_raw = (const float*)d_in[3];
    const float* th_raw = (const float*)d_in[4];
    const float* sr_raw = (const float*)d_in[5];
    float* out = (float*)d_out;                    // [1,384,256,256]

    char* ws = (char*)d_ws;
    _Float16* feat16 = (_Float16*)ws;                    // 192 KB @ 0
    float4*   PA     = (float4*)(ws + 196608);           // 4 KB
    float4*   PB     = (float4*)(ws + 200704);           // 4 KB
    float*    PS     = (float*)(ws + 204800);            // 1 KB
    _Float16* LCtab  = (_Float16*)(ws + 205824);         // 1 MB (128 x 8 KB)

    setup_all<<<177, 256, 0, stream>>>(feat, guide, sx_raw, sy_raw, th_raw,
                                       sr_raw, feat16, PA, PB, PS, LCtab);
    jbu_main<<<dim3(8, 256), 512, 0, stream>>>(guide, feat16, PA, PB, PS,
                                               LCtab, out);
}